// Round 16
// baseline (801.222 us; speedup 1.0000x reference)
//
#include <hip/hip_runtime.h>
#include <cstdint>
#include <cstddef>

#define NN 50000
#define NE 800000
#define NG 256
#define NLAY 7
#define NBLK 782   // 64-row tiles
#define CAP 18432  // bins capacity per dst-range (mean 16327, +16 sigma)

typedef float f32x4 __attribute__((ext_vector_type(4)));
typedef __bf16 bf16x8 __attribute__((ext_vector_type(8)));
typedef _Float16 h16x8 __attribute__((ext_vector_type(8)));

__device__ __forceinline__ float4 ld4(const float* p) { return *(const float4*)p; }
__device__ __forceinline__ void addh8(float4& x, float4& y, h16x8 v) {
  x.x += (float)v[0]; x.y += (float)v[1]; x.z += (float)v[2]; x.w += (float)v[3];
  y.x += (float)v[4]; y.y += (float)v[5]; y.z += (float)v[6]; y.w += (float)v[7];
}

// ---------------- init: zeros + hb=fp16(x) + W1/W2 transpose+split + gcur --------
__global__ void k_init(const float* __restrict__ x, const float* __restrict__ W1,
                       const float* __restrict__ W2, int* __restrict__ counts,
                       int* __restrict__ gcur, float* __restrict__ pooled,
                       _Float16* __restrict__ hb,
                       __bf16* __restrict__ w1h, __bf16* __restrict__ w1l,
                       __bf16* __restrict__ w2h, __bf16* __restrict__ w2l) {
  int i = blockIdx.x * 256 + threadIdx.x;  // grid 25000 -> 6.4M
  if (i < NN) counts[i] = 0;
  if (i < 49) gcur[i] = i * CAP;
  if (i < NG * 1792) pooled[i] = 0.f;
  if (i < NN * 128) hb[i] = (_Float16)x[i];
  if (i < NLAY * 16384) {
    int l = i >> 14, r = i & 16383;
    int n = r >> 7, k = r & 127;
    float a = W1[l * 16384 + k * 128 + n];
    __bf16 ah = (__bf16)a;
    w1h[i] = ah;
    w1l[i] = (__bf16)(a - (float)ah);
    float b = W2[l * 16384 + k * 128 + n];
    __bf16 bh = (__bf16)b;
    w2h[i] = bh;
    w2l[i] = (__bf16)(b - (float)bh);
  }
}

__global__ void k_hist(const int* __restrict__ edge, int* __restrict__ counts) {
  int e = blockIdx.x * 256 + threadIdx.x;
  if (e < NE) atomicAdd(&counts[edge[NE + e]], 1);
}

// ---------------- parallel CSR scan ----------------
__global__ void k_part(const int* __restrict__ counts, int* __restrict__ bsum) {
  __shared__ int sm[256];
  int b = blockIdx.x, t = threadIdx.x;
  int i = b * 256 + t;
  sm[t] = (i < NN) ? counts[i] : 0;
  __syncthreads();
  for (int s = 128; s > 0; s >>= 1) {
    if (t < s) sm[t] += sm[t + s];
    __syncthreads();
  }
  if (t == 0) bsum[b] = sm[0];
}

__global__ void k_bscan(const int* __restrict__ bsum, int* __restrict__ boff,
                        int* __restrict__ row_ptr) {
  __shared__ int sm[256];
  int t = threadIdx.x;
  int v = (t < 196) ? bsum[t] : 0;
  sm[t] = v;
  __syncthreads();
  int val = v;
  for (int off = 1; off < 256; off <<= 1) {
    int o = (t >= off) ? sm[t - off] : 0;
    __syncthreads();
    val += o;
    sm[t] = val;
    __syncthreads();
  }
  if (t < 196) boff[t] = val - v;  // exclusive
  if (t == 255) row_ptr[NN] = val; // total = NE
}

__global__ void k_rowptr(const int* __restrict__ counts, const int* __restrict__ boff,
                         int* __restrict__ row_ptr) {
  __shared__ int sm[256];
  int b = blockIdx.x, t = threadIdx.x;
  int i = b * 256 + t;
  int c = (i < NN) ? counts[i] : 0;
  sm[t] = c;
  __syncthreads();
  int val = c;
  for (int off = 1; off < 256; off <<= 1) {
    int o = (t >= off) ? sm[t - off] : 0;
    __syncthreads();
    val += o;
    sm[t] = val;
    __syncthreads();
  }
  if (i < NN) row_ptr[i] = val - c + boff[b];
}

// ---------------- binned CSR build, pass A: block-private slice append ----------
__global__ __launch_bounds__(256) void k_binA(const int* __restrict__ edge,
                                              int* __restrict__ gcur,
                                              unsigned int* __restrict__ bins) {
  __shared__ int lh[49], lbase[49], lt[49];
  const int tid = threadIdx.x;
  const int e0 = blockIdx.x * 3125, e1 = e0 + 3125;
  if (tid < 49) { lh[tid] = 0; lt[tid] = 0; }
  __syncthreads();
  for (int e = e0 + tid; e < e1; e += 256)
    atomicAdd(&lh[edge[NE + e] >> 10], 1);
  __syncthreads();
  if (tid < 49) lbase[tid] = atomicAdd(&gcur[tid], lh[tid]);
  __syncthreads();
  for (int e = e0 + tid; e < e1; e += 256) {
    int dst = edge[NE + e], src = edge[e];
    int r = dst >> 10;
    int t = atomicAdd(&lt[r], 1);
    bins[lbase[r] + t] = ((unsigned)dst << 16) | (unsigned)src;
  }
}

// pass B: one block per 1024-node range; LDS scatter + per-row src sort + writeout.
// Sorting each row's sources ascending gives the gather src-locality: all blocks
// sweep src space low->high together, so the hot band fits per-XCD L2.
__global__ __launch_bounds__(512) void k_binB(const int* __restrict__ row_ptr,
                                              const int* __restrict__ gcur,
                                              const unsigned int* __restrict__ bins,
                                              unsigned short* __restrict__ csr16) {
  __shared__ int lcur[1024];
  __shared__ unsigned short lcsr[24576];  // 48 KB
  const int blk = blockIdx.x, tid = threadIdx.x;
  const int base = blk << 10;
  const int nn = (base + 1024 <= NN) ? 1024 : (NN - base);
  const int seg0 = row_ptr[base];
  const int seg1 = row_ptr[(base + 1024 <= NN) ? (base + 1024) : NN];
  for (int i = tid; i < nn; i += 512) lcur[i] = row_ptr[base + i] - seg0;
  __syncthreads();
  const int tot = gcur[blk] - blk * CAP;
  for (int t = tid; t < tot; t += 512) {
    unsigned int p = bins[blk * CAP + t];
    int dst = (int)(p >> 16), src = (int)(p & 0xffffu);
    int pos = atomicAdd(&lcur[dst - base], 1);
    lcsr[pos] = (unsigned short)src;
  }
  __syncthreads();
  // insertion-sort each row's sources ascending (one-time prep cost)
  for (int i = tid; i < nn; i += 512) {
    int s0 = row_ptr[base + i] - seg0;
    int s1 = lcur[i];  // end offset after scatter
    for (int a = s0 + 1; a < s1; ++a) {
      unsigned short v = lcsr[a];
      int b = a - 1;
      while (b >= s0 && lcsr[b] > v) { lcsr[b + 1] = lcsr[b]; --b; }
      lcsr[b + 1] = v;
    }
  }
  __syncthreads();
  for (int i = tid; i < seg1 - seg0; i += 512) csr16[seg0 + i] = lcsr[i];
}

// ---------------- split fp32x8 -> bf16 hi/lo fragments ----------------
__device__ __forceinline__ void split8(const float4 v0, const float4 v1,
                                       bf16x8& hi, bf16x8& lo) {
  float f[8] = {v0.x, v0.y, v0.z, v0.w, v1.x, v1.y, v1.z, v1.w};
  #pragma unroll
  for (int j = 0; j < 8; ++j) {
    __bf16 h = (__bf16)f[j];
    hi[j] = h;
    lo[j] = (__bf16)(f[j] - (float)h);
  }
}

// ---------------- shared MFMA phase: LDS-staged, lane-swizzled B fragments --------
__device__ __forceinline__ void mfma_phase(
    int tid, const __bf16* __restrict__ wth, const __bf16* __restrict__ wtl,
    float (*zs)[132], __bf16* wfr, f32x4 acc[4])
{
  const int wv = tid >> 6, stripe = wv >> 1, half = wv & 1;
  const int lane = tid & 63, q = lane >> 4, m = lane & 15;
  #pragma unroll 1
  for (int kc = 0; kc < 4; ++kc) {
    __syncthreads();
    #pragma unroll
    for (int it = 0; it < 2; ++it) {
      int fid = tid + it * 512;
      int ln = fid & 63, slot = fid >> 6;
      int hl = slot & 1, ctp = (slot >> 1) & 3, hfp = slot >> 3;
      int n = hfp * 64 + ctp * 16 + (ln & 15);
      int k = kc * 32 + (ln >> 4) * 8;
      const __bf16* src = (hl ? wtl : wth) + n * 128 + k;
      *(bf16x8*)&wfr[(size_t)fid * 8] = *(const bf16x8*)src;
    }
    __syncthreads();
    const int k0 = kc * 32 + q * 8;
    float4 v0 = *(const float4*)&zs[stripe * 16 + m][k0];
    float4 v1 = *(const float4*)&zs[stripe * 16 + m][k0 + 4];
    bf16x8 ah, al;
    split8(v0, v1, ah, al);
    #pragma unroll
    for (int ct = 0; ct < 4; ++ct) {
      int sbase = (half * 4 + ct) * 2;
      bf16x8 bh = *(const bf16x8*)&wfr[(size_t)(sbase * 64 + lane) * 8];
      bf16x8 bl = *(const bf16x8*)&wfr[(size_t)((sbase + 1) * 64 + lane) * 8];
      acc[ct] = __builtin_amdgcn_mfma_f32_16x16x32_bf16(ah, bh, acc[ct], 0, 0, 0);
      acc[ct] = __builtin_amdgcn_mfma_f32_16x16x32_bf16(ah, bl, acc[ct], 0, 0, 0);
      acc[ct] = __builtin_amdgcn_mfma_f32_16x16x32_bf16(al, bh, acc[ct], 0, 0, 0);
    }
  }
  __syncthreads();
}

// ---------------- FUSED1: fp16 gather (x4 unroll) -> LDS -> MFMA GEMM1 -> fp16 z1 --
__global__ __launch_bounds__(512) void k_fused1(
    const _Float16* __restrict__ hb, const int* __restrict__ row_ptr,
    const unsigned short* __restrict__ csr_src,
    const __bf16* __restrict__ wth, const __bf16* __restrict__ wtl,
    const float* __restrict__ bias, _Float16* __restrict__ zb,
    float* __restrict__ psum, float* __restrict__ psq)
{
  __shared__ float zs[64][132];
  __shared__ __bf16 wfr[8192];
  const int tid = threadIdx.x;
  const int m0 = blockIdx.x * 64;

  // ---- phase 1: gather agg = h[r] + sum h[src]; 8 thr/row, 4 edges in flight ----
  {
    const int lr = tid >> 3;     // 0..63
    const int sub = tid & 7;     // 16 cols each
    const int r = m0 + lr;
    const int c0 = sub << 4;
    float4 a0 = make_float4(0,0,0,0), a1 = a0, a2 = a0, a3 = a0;
    float4 b0 = a0, b1 = a0, b2 = a0, b3 = a0;
    if (r < NN) {
      const _Float16* hp = hb + ((size_t)r << 7) + c0;
      addh8(a0, a1, *(const h16x8*)hp);
      addh8(a2, a3, *(const h16x8*)(hp + 8));
      int e = row_ptr[r], e1 = row_ptr[r + 1];
      for (; e + 3 < e1; e += 4) {
        const _Float16* p0 = hb + ((size_t)csr_src[e] << 7) + c0;
        const _Float16* p1 = hb + ((size_t)csr_src[e + 1] << 7) + c0;
        const _Float16* p2 = hb + ((size_t)csr_src[e + 2] << 7) + c0;
        const _Float16* p3 = hb + ((size_t)csr_src[e + 3] << 7) + c0;
        h16x8 v0a = *(const h16x8*)p0, v0b = *(const h16x8*)(p0 + 8);
        h16x8 v1a = *(const h16x8*)p1, v1b = *(const h16x8*)(p1 + 8);
        h16x8 v2a = *(const h16x8*)p2, v2b = *(const h16x8*)(p2 + 8);
        h16x8 v3a = *(const h16x8*)p3, v3b = *(const h16x8*)(p3 + 8);
        addh8(a0, a1, v0a); addh8(a2, a3, v0b);
        addh8(b0, b1, v1a); addh8(b2, b3, v1b);
        addh8(a0, a1, v2a); addh8(a2, a3, v2b);
        addh8(b0, b1, v3a); addh8(b2, b3, v3b);
      }
      for (; e < e1; ++e) {
        const _Float16* p0 = hb + ((size_t)csr_src[e] << 7) + c0;
        addh8(a0, a1, *(const h16x8*)p0);
        addh8(a2, a3, *(const h16x8*)(p0 + 8));
      }
      a0.x += b0.x; a0.y += b0.y; a0.z += b0.z; a0.w += b0.w;
      a1.x += b1.x; a1.y += b1.y; a1.z += b1.z; a1.w += b1.w;
      a2.x += b2.x; a2.y += b2.y; a2.z += b2.z; a2.w += b2.w;
      a3.x += b3.x; a3.y += b3.y; a3.z += b3.z; a3.w += b3.w;
    }
    *(float4*)&zs[lr][c0 + 0] = a0;
    *(float4*)&zs[lr][c0 + 4] = a1;
    *(float4*)&zs[lr][c0 + 8] = a2;
    *(float4*)&zs[lr][c0 + 12] = a3;
  }
  __syncthreads();

  // ---- phase 2: MFMA with LDS-staged B ----
  const int wv = tid >> 6, stripe = wv >> 1, half = wv & 1;
  const int lane = tid & 63, q = lane >> 4, m = lane & 15;
  f32x4 acc[4] = {};
  mfma_phase(tid, wth, wtl, zs, wfr, acc);

  // ---- epilogue: bias, fp16 z1 store, BN partials ----
  float* red_s = (float*)zs;          // 128*17
  float* red_q = red_s + 2176;        // 128*17
  const int sl = stripe * 4 + q;      // 16 partial slots per column
  #pragma unroll
  for (int ct = 0; ct < 4; ++ct) {
    const int col = half * 64 + ct * 16 + m;
    const float bb = bias[col];
    float s = 0.f, qq = 0.f;
    #pragma unroll
    for (int i = 0; i < 4; ++i) {
      int r = m0 + stripe * 16 + q * 4 + i;
      if (r < NN) {
        float o = acc[ct][i] + bb;
        zb[((size_t)r << 7) + col] = (_Float16)o;
        s += o; qq += o * o;
      }
    }
    red_s[col * 17 + sl] = s;
    red_q[col * 17 + sl] = qq;
  }
  __syncthreads();
  if (tid < 128) {
    float s = 0.f, qq = 0.f;
    #pragma unroll
    for (int k = 0; k < 16; ++k) {
      s += red_s[tid * 17 + k];
      qq += red_q[tid * 17 + k];
    }
    psum[blockIdx.x * 128 + tid] = s;
    psq[blockIdx.x * 128 + tid] = qq;
  }
}

// ---------------- BN finalize (parallel): one block per column ----------------
__global__ __launch_bounds__(256) void k_bnfin(
    const float* __restrict__ psum, const float* __restrict__ psq,
    const float* __restrict__ gamma, const float* __restrict__ beta,
    float* __restrict__ ab) {
  __shared__ float ss[256], sq[256];
  int col = blockIdx.x;   // 128
  int t = threadIdx.x;    // 256
  float s = 0.f, q = 0.f;
  for (int b = t; b < NBLK; b += 256) {
    s += psum[b * 128 + col];
    q += psq[b * 128 + col];
  }
  ss[t] = s; sq[t] = q;
  __syncthreads();
  for (int st = 128; st > 0; st >>= 1) {
    if (t < st) { ss[t] += ss[t + st]; sq[t] += sq[t + st]; }
    __syncthreads();
  }
  if (t == 0) {
    float mean = ss[0] * (1.f / NN);
    float var = sq[0] * (1.f / NN) - mean * mean;
    float rstd = rsqrtf(var + 1e-5f);
    float a = gamma[col] * rstd;
    ab[col] = a;
    ab[128 + col] = beta[col] - mean * a;
  }
}

// ---------------- FUSED2: affine+relu(fp16 z1) -> LDS -> MFMA GEMM2 -> fp16 h + pool
__global__ __launch_bounds__(512) void k_fused2(
    const _Float16* __restrict__ zb, const float* __restrict__ ab,
    const __bf16* __restrict__ wth, const __bf16* __restrict__ wtl,
    const float* __restrict__ bias, _Float16* __restrict__ hb,
    const int* __restrict__ batch, float* __restrict__ pooled, int layer)
{
  __shared__ float zs[64][132];
  __shared__ __bf16 wfr[8192];
  const int tid = threadIdx.x;
  const int m0 = blockIdx.x * 64;

  // ---- phase 1: coalesced fp16 load + vector affine + relu -> zs ----
  {
    const int lr = tid >> 3;     // 0..63
    const int sub = tid & 7;     // 16 cols
    const int r = m0 + lr;
    const int c0 = sub << 4;
    h16x8 u0 = {}, u1 = {};
    if (r < NN) {
      const _Float16* rp = zb + ((size_t)r << 7) + c0;
      u0 = *(const h16x8*)rp;
      u1 = *(const h16x8*)(rp + 8);
    }
    float4 v0 = make_float4((float)u0[0], (float)u0[1], (float)u0[2], (float)u0[3]);
    float4 v1 = make_float4((float)u0[4], (float)u0[5], (float)u0[6], (float)u0[7]);
    float4 v2 = make_float4((float)u1[0], (float)u1[1], (float)u1[2], (float)u1[3]);
    float4 v3 = make_float4((float)u1[4], (float)u1[5], (float)u1[6], (float)u1[7]);
    float4 s0 = ld4(ab + c0), s1 = ld4(ab + c0 + 4);
    float4 s2 = ld4(ab + c0 + 8), s3 = ld4(ab + c0 + 12);
    float4 o0 = ld4(ab + 128 + c0), o1 = ld4(ab + 128 + c0 + 4);
    float4 o2 = ld4(ab + 128 + c0 + 8), o3 = ld4(ab + 128 + c0 + 12);
    float4 y0, y1, y2, y3;
    y0.x = fmaxf(fmaf(s0.x, v0.x, o0.x), 0.f); y0.y = fmaxf(fmaf(s0.y, v0.y, o0.y), 0.f);
    y0.z = fmaxf(fmaf(s0.z, v0.z, o0.z), 0.f); y0.w = fmaxf(fmaf(s0.w, v0.w, o0.w), 0.f);
    y1.x = fmaxf(fmaf(s1.x, v1.x, o1.x), 0.f); y1.y = fmaxf(fmaf(s1.y, v1.y, o1.y), 0.f);
    y1.z = fmaxf(fmaf(s1.z, v1.z, o1.z), 0.f); y1.w = fmaxf(fmaf(s1.w, v1.w, o1.w), 0.f);
    y2.x = fmaxf(fmaf(s2.x, v2.x, o2.x), 0.f); y2.y = fmaxf(fmaf(s2.y, v2.y, o2.y), 0.f);
    y2.z = fmaxf(fmaf(s2.z, v2.z, o2.z), 0.f); y2.w = fmaxf(fmaf(s2.w, v2.w, o2.w), 0.f);
    y3.x = fmaxf(fmaf(s3.x, v3.x, o3.x), 0.f); y3.y = fmaxf(fmaf(s3.y, v3.y, o3.y), 0.f);
    y3.z = fmaxf(fmaf(s3.z, v3.z, o3.z), 0.f); y3.w = fmaxf(fmaf(s3.w, v3.w, o3.w), 0.f);
    *(float4*)&zs[lr][c0 + 0] = y0;
    *(float4*)&zs[lr][c0 + 4] = y1;
    *(float4*)&zs[lr][c0 + 8] = y2;
    *(float4*)&zs[lr][c0 + 12] = y3;
  }
  __syncthreads();

  // ---- phase 2: MFMA with LDS-staged B ----
  const int wv = tid >> 6, stripe = wv >> 1, half = wv & 1;
  const int lane = tid & 63, q = lane >> 4, m = lane & 15;
  f32x4 acc[4] = {};
  mfma_phase(tid, wth, wtl, zs, wfr, acc);

  // ---- epilogue: bias+relu, fp16 h store, pooling ----
  int bg[4];
  #pragma unroll
  for (int i = 0; i < 4; ++i) {
    int r = m0 + stripe * 16 + q * 4 + i;
    bg[i] = (r < NN) ? batch[r] : -1;
  }
  #pragma unroll
  for (int ct = 0; ct < 4; ++ct) {
    const int col = half * 64 + ct * 16 + m;
    const float bb = bias[col];
    #pragma unroll
    for (int i = 0; i < 4; ++i) {
      int r = m0 + stripe * 16 + q * 4 + i;
      float v = fmaxf(acc[ct][i] + bb, 0.f);
      acc[ct][i] = v;
      if (r < NN) hb[((size_t)r << 7) + col] = (_Float16)v;
    }
  }

  int gstart = batch[m0];
  int gend = batch[(m0 + 63 < NN) ? (m0 + 63) : (NN - 1)];
  float* red_s = (float*)zs;          // 128*17
  float* red_m = red_s + 2176;        // 128*17
  const int sl = stripe * 4 + q;
  for (int g = gstart; g <= gend; ++g) {
    __syncthreads();
    #pragma unroll
    for (int ct = 0; ct < 4; ++ct) {
      const int col = half * 64 + ct * 16 + m;
      float s = 0.f, mx = 0.f;
      #pragma unroll
      for (int i = 0; i < 4; ++i) {
        if (bg[i] == g) { s += acc[ct][i]; mx = fmaxf(mx, acc[ct][i]); }
      }
      red_s[col * 17 + sl] = s;
      red_m[col * 17 + sl] = mx;
    }
    __syncthreads();
    if (tid < 128) {
      float s = 0.f, mx = 0.f;
      #pragma unroll
      for (int k = 0; k < 16; ++k) {
        s += red_s[tid * 17 + k];
        mx = fmaxf(mx, red_m[tid * 17 + k]);
      }
      if (s != 0.f) atomicAdd(&pooled[g * 1792 + layer * 128 + tid], s);
      if (mx != 0.f)
        atomicMax((int*)&pooled[g * 1792 + 896 + layer * 128 + tid], __float_as_int(mx));
    }
  }
}

// ---------------- Wl1 prep: transpose + split via LDS tiles ----------------
__global__ __launch_bounds__(256) void k_wl1prep(
    const float* __restrict__ Wl1, __bf16* __restrict__ wh, __bf16* __restrict__ wl) {
  __shared__ float tile[32][33];
  const int k0 = blockIdx.x * 32, n0 = blockIdx.y * 32;
  const int lr = threadIdx.x >> 5, lc = threadIdx.x & 31;
  #pragma unroll
  for (int it = 0; it < 4; ++it) {
    int rr = lr + it * 8;
    tile[rr][lc] = Wl1[(size_t)(k0 + rr) * 1792 + n0 + lc];
  }
  __syncthreads();
  #pragma unroll
  for (int it = 0; it < 4; ++it) {
    int rr = lr + it * 8;
    float v = tile[lc][rr];
    __bf16 h = (__bf16)v;
    wh[(size_t)(n0 + rr) * 1792 + k0 + lc] = h;
    wl[(size_t)(n0 + rr) * 1792 + k0 + lc] = (__bf16)(v - (float)h);
  }
}

// ---------------- MLP1 (MFMA split-bf16, split-K=4): part = pooled @ Wl1 ----------
__global__ __launch_bounds__(256) void k_mlp1a(
    const float* __restrict__ P, const __bf16* __restrict__ wh,
    const __bf16* __restrict__ wl, float* __restrict__ part)
{
  const int tid = threadIdx.x;
  const int n0 = blockIdx.x * 64;
  const int m0 = blockIdx.y * 64;
  const int kc = blockIdx.z;          // 0..3, chunk of 448 k
  const int kbase = kc * 448;
  const int w = tid >> 6, lane = tid & 63, q = lane >> 4, m = lane & 15;
  const int row = m0 + w * 16 + m;    // < 256 always
  f32x4 acc[4] = {};
  const float* rp = P + (size_t)row * 1792;
  #pragma unroll 2
  for (int ks = 0; ks < 14; ++ks) {
    const int k0 = kbase + ks * 32 + q * 8;
    float4 v0 = ld4(rp + k0), v1 = ld4(rp + k0 + 4);
    bf16x8 ah, al;
    split8(v0, v1, ah, al);
    #pragma unroll
    for (int ct = 0; ct < 4; ++ct) {
      const int n = n0 + ct * 16 + m;
      bf16x8 bh = *(const bf16x8*)(wh + (size_t)n * 1792 + k0);
      bf16x8 bl = *(const bf16x8*)(wl + (size_t)n * 1792 + k0);
      acc[ct] = __builtin_amdgcn_mfma_f32_16x16x32_bf16(ah, bh, acc[ct], 0, 0, 0);
      acc[ct] = __builtin_amdgcn_mfma_f32_16x16x32_bf16(ah, bl, acc[ct], 0, 0, 0);
      acc[ct] = __builtin_amdgcn_mfma_f32_16x16x32_bf16(al, bh, acc[ct], 0, 0, 0);
    }
  }
  float* pp = part + (size_t)kc * 458752;
  #pragma unroll
  for (int ct = 0; ct < 4; ++ct) {
    const int n = n0 + ct * 16 + m;
    #pragma unroll
    for (int i = 0; i < 4; ++i) {
      int r = m0 + w * 16 + q * 4 + i;
      pp[(size_t)r * 1792 + n] = acc[ct][i];
    }
  }
}

__global__ void k_mlp1b(const float* __restrict__ part, const float* __restrict__ bl1,
                        float* __restrict__ hfin) {
  int idx = blockIdx.x * 256 + threadIdx.x;
  int n = idx % 1792;
  float s = bl1[n];
  #pragma unroll
  for (int kc = 0; kc < 4; ++kc) s += part[(size_t)kc * 458752 + idx];
  hfin[idx] = fmaxf(s, 0.f);
}

__global__ void k_mlp2(const float* __restrict__ hfin, const float* __restrict__ Wl2,
                       const float* __restrict__ bl2, float* __restrict__ out) {
  __shared__ float red[256];
  int g = blockIdx.x, t = threadIdx.x;
  float p = 0.f;
  for (int k = t; k < 1792; k += 256) p += hfin[(size_t)g * 1792 + k] * Wl2[k];
  red[t] = p;
  __syncthreads();
  for (int s = 128; s > 0; s >>= 1) {
    if (t < s) red[t] += red[t + s];
    __syncthreads();
  }
  if (t == 0) {
    float l = red[0] + bl2[0];
    out[g] = 1.f / (1.f + expf(-l));
    out[NG + g] = l;
  }
}

// ---------------- launch ----------------
extern "C" void kernel_launch(void* const* d_in, const int* in_sizes, int n_in,
                              void* d_out, int out_size, void* d_ws, size_t ws_size,
                              hipStream_t stream) {
  const float* x     = (const float*)d_in[0];
  const int*   edge  = (const int*)d_in[1];
  const int*   batch = (const int*)d_in[2];
  const float* W1    = (const float*)d_in[3];
  const float* b1    = (const float*)d_in[4];
  const float* gamma = (const float*)d_in[5];
  const float* beta  = (const float*)d_in[6];
  const float* W2    = (const float*)d_in[7];
  const float* b2    = (const float*)d_in[8];
  const float* Wl1   = (const float*)d_in[9];
  const float* bl1   = (const float*)d_in[10];
  const float* Wl2   = (const float*)d_in[11];
  const float* bl2   = (const float*)d_in[12];
  float* out = (float*)d_out;

  int* wsi = (int*)d_ws;
  int* row_ptr = wsi;                 // 50048
  int* counts  = wsi + 50048;         // 50048
  int* bsum    = wsi + 100096;        // 256
  int* boff    = wsi + 100352;        // 256
  int* gcur    = wsi + 100608;        // 64 (pad to 100864)
  unsigned short* csr16 = (unsigned short*)(wsi + 100864);  // 800000 u16 = 400000 ints
  float* wsf   = (float*)(wsi + 950912);
  // float-region layout:
  _Float16* zb     = (_Float16*)wsf;            // [50000,128] fp16 z1 (3.2M floats)
  _Float16* hb     = (_Float16*)(wsf + 6400000);// [50000,128] fp16 h (3.2M floats)
  float*    part   = wsf + 9600000;             // [4][256][1792]
  float*    psum   = wsf + 12800000;            // [782,128]
  float*    psq    = wsf + 12900096;            // [782,128]
  float*    ab     = wsf + 13000192;            // [2,128]
  float*    pooled = wsf + 13000448;            // [256,1792] -> ends 13459200
  __bf16*   w1h    = (__bf16*)(wsf + 13459200); // 7*16384 bf16
  __bf16*   w1l    = (__bf16*)(wsf + 13516544);
  __bf16*   w2h    = (__bf16*)(wsf + 13573888);
  __bf16*   w2l    = (__bf16*)(wsf + 13631232); // ends 13688576
  // bins aliases zb region (dead until first fused1; binB completes before layers)
  unsigned int* bins = (unsigned int*)wsf;      // 49*18432 u32 = 3.6 MB << zb size
  // post-layer aliases (zb region dead after last k_fused2):
  __bf16*   wl1h   = (__bf16*)wsf;              // 1792*1792 bf16
  __bf16*   wl1l   = (__bf16*)(wsf + 1605632);  // ends 3,211,264
  float*    hfin   = wsf + 4000000;             // [256,1792]

  // prep: zeros + x->fp16 + W split + gcur; degree hist; CSR scan; binned fill
  k_init<<<25000, 256, 0, stream>>>(x, W1, W2, counts, gcur, pooled, hb,
                                    w1h, w1l, w2h, w2l);
  k_hist<<<3125, 256, 0, stream>>>(edge, counts);
  k_part<<<196, 256, 0, stream>>>(counts, bsum);
  k_bscan<<<1, 256, 0, stream>>>(bsum, boff, row_ptr);
  k_rowptr<<<196, 256, 0, stream>>>(counts, boff, row_ptr);
  k_binA<<<256, 256, 0, stream>>>(edge, gcur, bins);
  k_binB<<<49, 512, 0, stream>>>(row_ptr, gcur, bins, csr16);

  for (int i = 0; i < NLAY; ++i) {
    k_fused1<<<NBLK, 512, 0, stream>>>(hb, row_ptr, csr16,
                                       w1h + i * 16384, w1l + i * 16384,
                                       b1 + i * 128, zb, psum, psq);
    k_bnfin<<<128, 256, 0, stream>>>(psum, psq, gamma + i * 128, beta + i * 128, ab);
    k_fused2<<<NBLK, 512, 0, stream>>>(zb, ab, w2h + i * 16384, w2l + i * 16384,
                                       b2 + i * 128, hb, batch, pooled, i);
  }
  // MLP head (zb region reused for Wl1 split + hfin)
  k_wl1prep<<<dim3(56, 56), 256, 0, stream>>>(Wl1, wl1h, wl1l);
  k_mlp1a<<<dim3(28, 4, 4), 256, 0, stream>>>(pooled, wl1h, wl1l, part);
  k_mlp1b<<<1792, 256, 0, stream>>>(part, bl1, hfin);
  k_mlp2<<<256, 256, 0, stream>>>(hfin, Wl2, bl2, out);
}

// Round 17
// 775.537 us; speedup vs baseline: 1.0331x; 1.0331x over previous
//
#include <hip/hip_runtime.h>
#include <cstdint>
#include <cstddef>

#define NN 50000
#define NE 800000
#define NG 256
#define NLAY 7
#define NBLK 782   // 64-row tiles
#define CAP 18432  // bins capacity per dst-range (mean 16327, +16 sigma)

typedef float f32x4 __attribute__((ext_vector_type(4)));
typedef __bf16 bf16x8 __attribute__((ext_vector_type(8)));
typedef _Float16 h16x8 __attribute__((ext_vector_type(8)));

__device__ __forceinline__ float4 ld4(const float* p) { return *(const float4*)p; }
__device__ __forceinline__ void addh8(float4& x, float4& y, h16x8 v) {
  x.x += (float)v[0]; x.y += (float)v[1]; x.z += (float)v[2]; x.w += (float)v[3];
  y.x += (float)v[4]; y.y += (float)v[5]; y.z += (float)v[6]; y.w += (float)v[7];
}

// ---------------- init: zeros + hb=fp16(x) + W1/W2 transpose+split + gcur --------
__global__ void k_init(const float* __restrict__ x, const float* __restrict__ W1,
                       const float* __restrict__ W2, int* __restrict__ counts,
                       int* __restrict__ gcur, float* __restrict__ pooled,
                       _Float16* __restrict__ hb,
                       __bf16* __restrict__ w1h, __bf16* __restrict__ w1l,
                       __bf16* __restrict__ w2h, __bf16* __restrict__ w2l) {
  int i = blockIdx.x * 256 + threadIdx.x;  // grid 25000 -> 6.4M
  if (i < NN) counts[i] = 0;
  if (i < 49) gcur[i] = i * CAP;
  if (i < NG * 1792) pooled[i] = 0.f;
  if (i < NN * 128) hb[i] = (_Float16)x[i];
  if (i < NLAY * 16384) {
    int l = i >> 14, r = i & 16383;
    int n = r >> 7, k = r & 127;
    float a = W1[l * 16384 + k * 128 + n];
    __bf16 ah = (__bf16)a;
    w1h[i] = ah;
    w1l[i] = (__bf16)(a - (float)ah);
    float b = W2[l * 16384 + k * 128 + n];
    __bf16 bh = (__bf16)b;
    w2h[i] = bh;
    w2l[i] = (__bf16)(b - (float)bh);
  }
}

__global__ void k_hist(const int* __restrict__ edge, int* __restrict__ counts) {
  int e = blockIdx.x * 256 + threadIdx.x;
  if (e < NE) atomicAdd(&counts[edge[NE + e]], 1);
}

// ---------------- parallel CSR scan ----------------
__global__ void k_part(const int* __restrict__ counts, int* __restrict__ bsum) {
  __shared__ int sm[256];
  int b = blockIdx.x, t = threadIdx.x;
  int i = b * 256 + t;
  sm[t] = (i < NN) ? counts[i] : 0;
  __syncthreads();
  for (int s = 128; s > 0; s >>= 1) {
    if (t < s) sm[t] += sm[t + s];
    __syncthreads();
  }
  if (t == 0) bsum[b] = sm[0];
}

__global__ void k_bscan(const int* __restrict__ bsum, int* __restrict__ boff,
                        int* __restrict__ row_ptr) {
  __shared__ int sm[256];
  int t = threadIdx.x;
  int v = (t < 196) ? bsum[t] : 0;
  sm[t] = v;
  __syncthreads();
  int val = v;
  for (int off = 1; off < 256; off <<= 1) {
    int o = (t >= off) ? sm[t - off] : 0;
    __syncthreads();
    val += o;
    sm[t] = val;
    __syncthreads();
  }
  if (t < 196) boff[t] = val - v;  // exclusive
  if (t == 255) row_ptr[NN] = val; // total = NE
}

__global__ void k_rowptr(const int* __restrict__ counts, const int* __restrict__ boff,
                         int* __restrict__ row_ptr) {
  __shared__ int sm[256];
  int b = blockIdx.x, t = threadIdx.x;
  int i = b * 256 + t;
  int c = (i < NN) ? counts[i] : 0;
  sm[t] = c;
  __syncthreads();
  int val = c;
  for (int off = 1; off < 256; off <<= 1) {
    int o = (t >= off) ? sm[t - off] : 0;
    __syncthreads();
    val += o;
    sm[t] = val;
    __syncthreads();
  }
  if (i < NN) row_ptr[i] = val - c + boff[b];
}

// ---------------- binned CSR build, pass A: block-private slice append ----------
__global__ __launch_bounds__(256) void k_binA(const int* __restrict__ edge,
                                              int* __restrict__ gcur,
                                              unsigned int* __restrict__ bins) {
  __shared__ int lh[49], lbase[49], lt[49];
  const int tid = threadIdx.x;
  const int e0 = blockIdx.x * 3125, e1 = e0 + 3125;
  if (tid < 49) { lh[tid] = 0; lt[tid] = 0; }
  __syncthreads();
  for (int e = e0 + tid; e < e1; e += 256)
    atomicAdd(&lh[edge[NE + e] >> 10], 1);
  __syncthreads();
  if (tid < 49) lbase[tid] = atomicAdd(&gcur[tid], lh[tid]);
  __syncthreads();
  for (int e = e0 + tid; e < e1; e += 256) {
    int dst = edge[NE + e], src = edge[e];
    int r = dst >> 10;
    int t = atomicAdd(&lt[r], 1);
    bins[lbase[r] + t] = ((unsigned)dst << 16) | (unsigned)src;
  }
}

// pass B: one block per 1024-node range; LDS scatter + coalesced csr16 writeout.
__global__ __launch_bounds__(512) void k_binB(const int* __restrict__ row_ptr,
                                              const int* __restrict__ gcur,
                                              const unsigned int* __restrict__ bins,
                                              unsigned short* __restrict__ csr16) {
  __shared__ int lcur[1024];
  __shared__ unsigned short lcsr[24576];  // 48 KB
  const int blk = blockIdx.x, tid = threadIdx.x;
  const int base = blk << 10;
  const int nn = (base + 1024 <= NN) ? 1024 : (NN - base);
  const int seg0 = row_ptr[base];
  const int seg1 = row_ptr[(base + 1024 <= NN) ? (base + 1024) : NN];
  for (int i = tid; i < nn; i += 512) lcur[i] = row_ptr[base + i] - seg0;
  __syncthreads();
  const int tot = gcur[blk] - blk * CAP;
  for (int t = tid; t < tot; t += 512) {
    unsigned int p = bins[blk * CAP + t];
    int dst = (int)(p >> 16), src = (int)(p & 0xffffu);
    int pos = atomicAdd(&lcur[dst - base], 1);
    lcsr[pos] = (unsigned short)src;
  }
  __syncthreads();
  for (int i = tid; i < seg1 - seg0; i += 512) csr16[seg0 + i] = lcsr[i];
}

// ---------------- split fp32x8 -> bf16 hi/lo fragments ----------------
__device__ __forceinline__ void split8(const float4 v0, const float4 v1,
                                       bf16x8& hi, bf16x8& lo) {
  float f[8] = {v0.x, v0.y, v0.z, v0.w, v1.x, v1.y, v1.z, v1.w};
  #pragma unroll
  for (int j = 0; j < 8; ++j) {
    __bf16 h = (__bf16)f[j];
    hi[j] = h;
    lo[j] = (__bf16)(f[j] - (float)h);
  }
}

// ---------------- shared MFMA phase: LDS-staged, lane-swizzled B fragments --------
__device__ __forceinline__ void mfma_phase(
    int tid, const __bf16* __restrict__ wth, const __bf16* __restrict__ wtl,
    float (*zs)[132], __bf16* wfr, f32x4 acc[4])
{
  const int wv = tid >> 6, stripe = wv >> 1, half = wv & 1;
  const int lane = tid & 63, q = lane >> 4, m = lane & 15;
  #pragma unroll 1
  for (int kc = 0; kc < 4; ++kc) {
    __syncthreads();
    #pragma unroll
    for (int it = 0; it < 2; ++it) {
      int fid = tid + it * 512;
      int ln = fid & 63, slot = fid >> 6;
      int hl = slot & 1, ctp = (slot >> 1) & 3, hfp = slot >> 3;
      int n = hfp * 64 + ctp * 16 + (ln & 15);
      int k = kc * 32 + (ln >> 4) * 8;
      const __bf16* src = (hl ? wtl : wth) + n * 128 + k;
      *(bf16x8*)&wfr[(size_t)fid * 8] = *(const bf16x8*)src;
    }
    __syncthreads();
    const int k0 = kc * 32 + q * 8;
    float4 v0 = *(const float4*)&zs[stripe * 16 + m][k0];
    float4 v1 = *(const float4*)&zs[stripe * 16 + m][k0 + 4];
    bf16x8 ah, al;
    split8(v0, v1, ah, al);
    #pragma unroll
    for (int ct = 0; ct < 4; ++ct) {
      int sbase = (half * 4 + ct) * 2;
      bf16x8 bh = *(const bf16x8*)&wfr[(size_t)(sbase * 64 + lane) * 8];
      bf16x8 bl = *(const bf16x8*)&wfr[(size_t)((sbase + 1) * 64 + lane) * 8];
      acc[ct] = __builtin_amdgcn_mfma_f32_16x16x32_bf16(ah, bh, acc[ct], 0, 0, 0);
      acc[ct] = __builtin_amdgcn_mfma_f32_16x16x32_bf16(ah, bl, acc[ct], 0, 0, 0);
      acc[ct] = __builtin_amdgcn_mfma_f32_16x16x32_bf16(al, bh, acc[ct], 0, 0, 0);
    }
  }
  __syncthreads();
}

// ---------------- FUSED1: fp16 gather (x4 unroll) -> LDS -> MFMA GEMM1 -> fp16 z1 --
// blk0: block-index offset (grid split in two for profiling visibility).
__global__ __launch_bounds__(512) void k_fused1(
    const _Float16* __restrict__ hb, const int* __restrict__ row_ptr,
    const unsigned short* __restrict__ csr_src,
    const __bf16* __restrict__ wth, const __bf16* __restrict__ wtl,
    const float* __restrict__ bias, _Float16* __restrict__ zb,
    float* __restrict__ psum, float* __restrict__ psq, int blk0)
{
  __shared__ float zs[64][132];
  __shared__ __bf16 wfr[8192];
  const int tid = threadIdx.x;
  const int blk = blk0 + blockIdx.x;
  const int m0 = blk * 64;

  // ---- phase 1: gather agg = h[r] + sum h[src]; 8 thr/row, 4 edges in flight ----
  {
    const int lr = tid >> 3;     // 0..63
    const int sub = tid & 7;     // 16 cols each
    const int r = m0 + lr;
    const int c0 = sub << 4;
    float4 a0 = make_float4(0,0,0,0), a1 = a0, a2 = a0, a3 = a0;
    float4 b0 = a0, b1 = a0, b2 = a0, b3 = a0;
    if (r < NN) {
      const _Float16* hp = hb + ((size_t)r << 7) + c0;
      addh8(a0, a1, *(const h16x8*)hp);
      addh8(a2, a3, *(const h16x8*)(hp + 8));
      int e = row_ptr[r], e1 = row_ptr[r + 1];
      for (; e + 3 < e1; e += 4) {
        const _Float16* p0 = hb + ((size_t)csr_src[e] << 7) + c0;
        const _Float16* p1 = hb + ((size_t)csr_src[e + 1] << 7) + c0;
        const _Float16* p2 = hb + ((size_t)csr_src[e + 2] << 7) + c0;
        const _Float16* p3 = hb + ((size_t)csr_src[e + 3] << 7) + c0;
        h16x8 v0a = *(const h16x8*)p0, v0b = *(const h16x8*)(p0 + 8);
        h16x8 v1a = *(const h16x8*)p1, v1b = *(const h16x8*)(p1 + 8);
        h16x8 v2a = *(const h16x8*)p2, v2b = *(const h16x8*)(p2 + 8);
        h16x8 v3a = *(const h16x8*)p3, v3b = *(const h16x8*)(p3 + 8);
        addh8(a0, a1, v0a); addh8(a2, a3, v0b);
        addh8(b0, b1, v1a); addh8(b2, b3, v1b);
        addh8(a0, a1, v2a); addh8(a2, a3, v2b);
        addh8(b0, b1, v3a); addh8(b2, b3, v3b);
      }
      for (; e < e1; ++e) {
        const _Float16* p0 = hb + ((size_t)csr_src[e] << 7) + c0;
        addh8(a0, a1, *(const h16x8*)p0);
        addh8(a2, a3, *(const h16x8*)(p0 + 8));
      }
      a0.x += b0.x; a0.y += b0.y; a0.z += b0.z; a0.w += b0.w;
      a1.x += b1.x; a1.y += b1.y; a1.z += b1.z; a1.w += b1.w;
      a2.x += b2.x; a2.y += b2.y; a2.z += b2.z; a2.w += b2.w;
      a3.x += b3.x; a3.y += b3.y; a3.z += b3.z; a3.w += b3.w;
    }
    *(float4*)&zs[lr][c0 + 0] = a0;
    *(float4*)&zs[lr][c0 + 4] = a1;
    *(float4*)&zs[lr][c0 + 8] = a2;
    *(float4*)&zs[lr][c0 + 12] = a3;
  }
  __syncthreads();

  // ---- phase 2: MFMA with LDS-staged B ----
  const int wv = tid >> 6, stripe = wv >> 1, half = wv & 1;
  const int lane = tid & 63, q = lane >> 4, m = lane & 15;
  f32x4 acc[4] = {};
  mfma_phase(tid, wth, wtl, zs, wfr, acc);

  // ---- epilogue: bias, fp16 z1 store, BN partials ----
  float* red_s = (float*)zs;          // 128*17
  float* red_q = red_s + 2176;        // 128*17
  const int sl = stripe * 4 + q;      // 16 partial slots per column
  #pragma unroll
  for (int ct = 0; ct < 4; ++ct) {
    const int col = half * 64 + ct * 16 + m;
    const float bb = bias[col];
    float s = 0.f, qq = 0.f;
    #pragma unroll
    for (int i = 0; i < 4; ++i) {
      int r = m0 + stripe * 16 + q * 4 + i;
      if (r < NN) {
        float o = acc[ct][i] + bb;
        zb[((size_t)r << 7) + col] = (_Float16)o;
        s += o; qq += o * o;
      }
    }
    red_s[col * 17 + sl] = s;
    red_q[col * 17 + sl] = qq;
  }
  __syncthreads();
  if (tid < 128) {
    float s = 0.f, qq = 0.f;
    #pragma unroll
    for (int k = 0; k < 16; ++k) {
      s += red_s[tid * 17 + k];
      qq += red_q[tid * 17 + k];
    }
    psum[blk * 128 + tid] = s;
    psq[blk * 128 + tid] = qq;
  }
}

// ---------------- BN finalize (parallel): one block per column ----------------
__global__ __launch_bounds__(256) void k_bnfin(
    const float* __restrict__ psum, const float* __restrict__ psq,
    const float* __restrict__ gamma, const float* __restrict__ beta,
    float* __restrict__ ab) {
  __shared__ float ss[256], sq[256];
  int col = blockIdx.x;   // 128
  int t = threadIdx.x;    // 256
  float s = 0.f, q = 0.f;
  for (int b = t; b < NBLK; b += 256) {
    s += psum[b * 128 + col];
    q += psq[b * 128 + col];
  }
  ss[t] = s; sq[t] = q;
  __syncthreads();
  for (int st = 128; st > 0; st >>= 1) {
    if (t < st) { ss[t] += ss[t + st]; sq[t] += sq[t + st]; }
    __syncthreads();
  }
  if (t == 0) {
    float mean = ss[0] * (1.f / NN);
    float var = sq[0] * (1.f / NN) - mean * mean;
    float rstd = rsqrtf(var + 1e-5f);
    float a = gamma[col] * rstd;
    ab[col] = a;
    ab[128 + col] = beta[col] - mean * a;
  }
}

// ---------------- FUSED2: affine+relu(fp16 z1) -> LDS -> MFMA GEMM2 -> fp16 h + pool
__global__ __launch_bounds__(512) void k_fused2(
    const _Float16* __restrict__ zb, const float* __restrict__ ab,
    const __bf16* __restrict__ wth, const __bf16* __restrict__ wtl,
    const float* __restrict__ bias, _Float16* __restrict__ hb,
    const int* __restrict__ batch, float* __restrict__ pooled, int layer)
{
  __shared__ float zs[64][132];
  __shared__ __bf16 wfr[8192];
  const int tid = threadIdx.x;
  const int m0 = blockIdx.x * 64;

  // ---- phase 1: coalesced fp16 load + vector affine + relu -> zs ----
  {
    const int lr = tid >> 3;     // 0..63
    const int sub = tid & 7;     // 16 cols
    const int r = m0 + lr;
    const int c0 = sub << 4;
    h16x8 u0 = {}, u1 = {};
    if (r < NN) {
      const _Float16* rp = zb + ((size_t)r << 7) + c0;
      u0 = *(const h16x8*)rp;
      u1 = *(const h16x8*)(rp + 8);
    }
    float4 v0 = make_float4((float)u0[0], (float)u0[1], (float)u0[2], (float)u0[3]);
    float4 v1 = make_float4((float)u0[4], (float)u0[5], (float)u0[6], (float)u0[7]);
    float4 v2 = make_float4((float)u1[0], (float)u1[1], (float)u1[2], (float)u1[3]);
    float4 v3 = make_float4((float)u1[4], (float)u1[5], (float)u1[6], (float)u1[7]);
    float4 s0 = ld4(ab + c0), s1 = ld4(ab + c0 + 4);
    float4 s2 = ld4(ab + c0 + 8), s3 = ld4(ab + c0 + 12);
    float4 o0 = ld4(ab + 128 + c0), o1 = ld4(ab + 128 + c0 + 4);
    float4 o2 = ld4(ab + 128 + c0 + 8), o3 = ld4(ab + 128 + c0 + 12);
    float4 y0, y1, y2, y3;
    y0.x = fmaxf(fmaf(s0.x, v0.x, o0.x), 0.f); y0.y = fmaxf(fmaf(s0.y, v0.y, o0.y), 0.f);
    y0.z = fmaxf(fmaf(s0.z, v0.z, o0.z), 0.f); y0.w = fmaxf(fmaf(s0.w, v0.w, o0.w), 0.f);
    y1.x = fmaxf(fmaf(s1.x, v1.x, o1.x), 0.f); y1.y = fmaxf(fmaf(s1.y, v1.y, o1.y), 0.f);
    y1.z = fmaxf(fmaf(s1.z, v1.z, o1.z), 0.f); y1.w = fmaxf(fmaf(s1.w, v1.w, o1.w), 0.f);
    y2.x = fmaxf(fmaf(s2.x, v2.x, o2.x), 0.f); y2.y = fmaxf(fmaf(s2.y, v2.y, o2.y), 0.f);
    y2.z = fmaxf(fmaf(s2.z, v2.z, o2.z), 0.f); y2.w = fmaxf(fmaf(s2.w, v2.w, o2.w), 0.f);
    y3.x = fmaxf(fmaf(s3.x, v3.x, o3.x), 0.f); y3.y = fmaxf(fmaf(s3.y, v3.y, o3.y), 0.f);
    y3.z = fmaxf(fmaf(s3.z, v3.z, o3.z), 0.f); y3.w = fmaxf(fmaf(s3.w, v3.w, o3.w), 0.f);
    *(float4*)&zs[lr][c0 + 0] = y0;
    *(float4*)&zs[lr][c0 + 4] = y1;
    *(float4*)&zs[lr][c0 + 8] = y2;
    *(float4*)&zs[lr][c0 + 12] = y3;
  }
  __syncthreads();

  // ---- phase 2: MFMA with LDS-staged B ----
  const int wv = tid >> 6, stripe = wv >> 1, half = wv & 1;
  const int lane = tid & 63, q = lane >> 4, m = lane & 15;
  f32x4 acc[4] = {};
  mfma_phase(tid, wth, wtl, zs, wfr, acc);

  // ---- epilogue: bias+relu, fp16 h store, pooling ----
  int bg[4];
  #pragma unroll
  for (int i = 0; i < 4; ++i) {
    int r = m0 + stripe * 16 + q * 4 + i;
    bg[i] = (r < NN) ? batch[r] : -1;
  }
  #pragma unroll
  for (int ct = 0; ct < 4; ++ct) {
    const int col = half * 64 + ct * 16 + m;
    const float bb = bias[col];
    #pragma unroll
    for (int i = 0; i < 4; ++i) {
      int r = m0 + stripe * 16 + q * 4 + i;
      float v = fmaxf(acc[ct][i] + bb, 0.f);
      acc[ct][i] = v;
      if (r < NN) hb[((size_t)r << 7) + col] = (_Float16)v;
    }
  }

  int gstart = batch[m0];
  int gend = batch[(m0 + 63 < NN) ? (m0 + 63) : (NN - 1)];
  float* red_s = (float*)zs;          // 128*17
  float* red_m = red_s + 2176;        // 128*17
  const int sl = stripe * 4 + q;
  for (int g = gstart; g <= gend; ++g) {
    __syncthreads();
    #pragma unroll
    for (int ct = 0; ct < 4; ++ct) {
      const int col = half * 64 + ct * 16 + m;
      float s = 0.f, mx = 0.f;
      #pragma unroll
      for (int i = 0; i < 4; ++i) {
        if (bg[i] == g) { s += acc[ct][i]; mx = fmaxf(mx, acc[ct][i]); }
      }
      red_s[col * 17 + sl] = s;
      red_m[col * 17 + sl] = mx;
    }
    __syncthreads();
    if (tid < 128) {
      float s = 0.f, mx = 0.f;
      #pragma unroll
      for (int k = 0; k < 16; ++k) {
        s += red_s[tid * 17 + k];
        mx = fmaxf(mx, red_m[tid * 17 + k]);
      }
      if (s != 0.f) atomicAdd(&pooled[g * 1792 + layer * 128 + tid], s);
      if (mx != 0.f)
        atomicMax((int*)&pooled[g * 1792 + 896 + layer * 128 + tid], __float_as_int(mx));
    }
  }
}

// ---------------- Wl1 prep: transpose + split via LDS tiles ----------------
__global__ __launch_bounds__(256) void k_wl1prep(
    const float* __restrict__ Wl1, __bf16* __restrict__ wh, __bf16* __restrict__ wl) {
  __shared__ float tile[32][33];
  const int k0 = blockIdx.x * 32, n0 = blockIdx.y * 32;
  const int lr = threadIdx.x >> 5, lc = threadIdx.x & 31;
  #pragma unroll
  for (int it = 0; it < 4; ++it) {
    int rr = lr + it * 8;
    tile[rr][lc] = Wl1[(size_t)(k0 + rr) * 1792 + n0 + lc];
  }
  __syncthreads();
  #pragma unroll
  for (int it = 0; it < 4; ++it) {
    int rr = lr + it * 8;
    float v = tile[lc][rr];
    __bf16 h = (__bf16)v;
    wh[(size_t)(n0 + rr) * 1792 + k0 + lc] = h;
    wl[(size_t)(n0 + rr) * 1792 + k0 + lc] = (__bf16)(v - (float)h);
  }
}

// ---------------- MLP1 (MFMA split-bf16, split-K=4): part = pooled @ Wl1 ----------
__global__ __launch_bounds__(256) void k_mlp1a(
    const float* __restrict__ P, const __bf16* __restrict__ wh,
    const __bf16* __restrict__ wl, float* __restrict__ part)
{
  const int tid = threadIdx.x;
  const int n0 = blockIdx.x * 64;
  const int m0 = blockIdx.y * 64;
  const int kc = blockIdx.z;          // 0..3, chunk of 448 k
  const int kbase = kc * 448;
  const int w = tid >> 6, lane = tid & 63, q = lane >> 4, m = lane & 15;
  const int row = m0 + w * 16 + m;    // < 256 always
  f32x4 acc[4] = {};
  const float* rp = P + (size_t)row * 1792;
  #pragma unroll 2
  for (int ks = 0; ks < 14; ++ks) {
    const int k0 = kbase + ks * 32 + q * 8;
    float4 v0 = ld4(rp + k0), v1 = ld4(rp + k0 + 4);
    bf16x8 ah, al;
    split8(v0, v1, ah, al);
    #pragma unroll
    for (int ct = 0; ct < 4; ++ct) {
      const int n = n0 + ct * 16 + m;
      bf16x8 bh = *(const bf16x8*)(wh + (size_t)n * 1792 + k0);
      bf16x8 bl = *(const bf16x8*)(wl + (size_t)n * 1792 + k0);
      acc[ct] = __builtin_amdgcn_mfma_f32_16x16x32_bf16(ah, bh, acc[ct], 0, 0, 0);
      acc[ct] = __builtin_amdgcn_mfma_f32_16x16x32_bf16(ah, bl, acc[ct], 0, 0, 0);
      acc[ct] = __builtin_amdgcn_mfma_f32_16x16x32_bf16(al, bh, acc[ct], 0, 0, 0);
    }
  }
  float* pp = part + (size_t)kc * 458752;
  #pragma unroll
  for (int ct = 0; ct < 4; ++ct) {
    const int n = n0 + ct * 16 + m;
    #pragma unroll
    for (int i = 0; i < 4; ++i) {
      int r = m0 + w * 16 + q * 4 + i;
      pp[(size_t)r * 1792 + n] = acc[ct][i];
    }
  }
}

__global__ void k_mlp1b(const float* __restrict__ part, const float* __restrict__ bl1,
                        float* __restrict__ hfin) {
  int idx = blockIdx.x * 256 + threadIdx.x;
  int n = idx % 1792;
  float s = bl1[n];
  #pragma unroll
  for (int kc = 0; kc < 4; ++kc) s += part[(size_t)kc * 458752 + idx];
  hfin[idx] = fmaxf(s, 0.f);
}

__global__ void k_mlp2(const float* __restrict__ hfin, const float* __restrict__ Wl2,
                       const float* __restrict__ bl2, float* __restrict__ out) {
  __shared__ float red[256];
  int g = blockIdx.x, t = threadIdx.x;
  float p = 0.f;
  for (int k = t; k < 1792; k += 256) p += hfin[(size_t)g * 1792 + k] * Wl2[k];
  red[t] = p;
  __syncthreads();
  for (int s = 128; s > 0; s >>= 1) {
    if (t < s) red[t] += red[t + s];
    __syncthreads();
  }
  if (t == 0) {
    float l = red[0] + bl2[0];
    out[g] = 1.f / (1.f + expf(-l));
    out[NG + g] = l;
  }
}

// ---------------- launch ----------------
extern "C" void kernel_launch(void* const* d_in, const int* in_sizes, int n_in,
                              void* d_out, int out_size, void* d_ws, size_t ws_size,
                              hipStream_t stream) {
  const float* x     = (const float*)d_in[0];
  const int*   edge  = (const int*)d_in[1];
  const int*   batch = (const int*)d_in[2];
  const float* W1    = (const float*)d_in[3];
  const float* b1    = (const float*)d_in[4];
  const float* gamma = (const float*)d_in[5];
  const float* beta  = (const float*)d_in[6];
  const float* W2    = (const float*)d_in[7];
  const float* b2    = (const float*)d_in[8];
  const float* Wl1   = (const float*)d_in[9];
  const float* bl1   = (const float*)d_in[10];
  const float* Wl2   = (const float*)d_in[11];
  const float* bl2   = (const float*)d_in[12];
  float* out = (float*)d_out;

  int* wsi = (int*)d_ws;
  int* row_ptr = wsi;                 // 50048
  int* counts  = wsi + 50048;         // 50048
  int* bsum    = wsi + 100096;        // 256
  int* boff    = wsi + 100352;        // 256
  int* gcur    = wsi + 100608;        // 64 (pad to 100864)
  unsigned short* csr16 = (unsigned short*)(wsi + 100864);  // 800000 u16 = 400000 ints
  float* wsf   = (float*)(wsi + 950912);
  // float-region layout:
  _Float16* zb     = (_Float16*)wsf;            // [50000,128] fp16 z1 (3.2M floats)
  _Float16* hb     = (_Float16*)(wsf + 6400000);// [50000,128] fp16 h (3.2M floats)
  float*    part   = wsf + 9600000;             // [4][256][1792]
  float*    psum   = wsf + 12800000;            // [782,128]
  float*    psq    = wsf + 12900096;            // [782,128]
  float*    ab     = wsf + 13000192;            // [2,128]
  float*    pooled = wsf + 13000448;            // [256,1792] -> ends 13459200
  __bf16*   w1h    = (__bf16*)(wsf + 13459200); // 7*16384 bf16
  __bf16*   w1l    = (__bf16*)(wsf + 13516544);
  __bf16*   w2h    = (__bf16*)(wsf + 13573888);
  __bf16*   w2l    = (__bf16*)(wsf + 13631232); // ends 13688576
  // bins aliases zb region (dead until first fused1; binB completes before layers)
  unsigned int* bins = (unsigned int*)wsf;      // 49*18432 u32 = 3.6 MB << zb size
  // post-layer aliases (zb region dead after last k_fused2):
  __bf16*   wl1h   = (__bf16*)wsf;              // 1792*1792 bf16
  __bf16*   wl1l   = (__bf16*)(wsf + 1605632);  // ends 3,211,264
  float*    hfin   = wsf + 4000000;             // [256,1792]

  // prep: zeros + x->fp16 + W split + gcur; degree hist; CSR scan; binned fill
  k_init<<<25000, 256, 0, stream>>>(x, W1, W2, counts, gcur, pooled, hb,
                                    w1h, w1l, w2h, w2l);
  k_hist<<<3125, 256, 0, stream>>>(edge, counts);
  k_part<<<196, 256, 0, stream>>>(counts, bsum);
  k_bscan<<<1, 256, 0, stream>>>(bsum, boff, row_ptr);
  k_rowptr<<<196, 256, 0, stream>>>(counts, boff, row_ptr);
  k_binA<<<256, 256, 0, stream>>>(edge, gcur, bins);
  k_binB<<<49, 512, 0, stream>>>(row_ptr, gcur, bins, csr16);

  for (int i = 0; i < NLAY; ++i) {
    // fused1 split into two half-grids (observability: lets fused2 into top-5)
    k_fused1<<<391, 512, 0, stream>>>(hb, row_ptr, csr16,
                                      w1h + i * 16384, w1l + i * 16384,
                                      b1 + i * 128, zb, psum, psq, 0);
    k_fused1<<<391, 512, 0, stream>>>(hb, row_ptr, csr16,
                                      w1h + i * 16384, w1l + i * 16384,
                                      b1 + i * 128, zb, psum, psq, 391);
    k_bnfin<<<128, 256, 0, stream>>>(psum, psq, gamma + i * 128, beta + i * 128, ab);
    k_fused2<<<NBLK, 512, 0, stream>>>(zb, ab, w2h + i * 16384, w2l + i * 16384,
                                       b2 + i * 128, hb, batch, pooled, i);
  }
  // MLP head (zb region reused for Wl1 split + hfin)
  k_wl1prep<<<dim3(56, 56), 256, 0, stream>>>(Wl1, wl1h, wl1l);
  k_mlp1a<<<dim3(28, 4, 4), 256, 0, stream>>>(pooled, wl1h, wl1l, part);
  k_mlp1b<<<1792, 256, 0, stream>>>(part, bl1, hfin);
  k_mlp2<<<256, 256, 0, stream>>>(hfin, Wl2, bl2, out);
}

// Round 18
// 717.208 us; speedup vs baseline: 1.1171x; 1.0813x over previous
//
#include <hip/hip_runtime.h>
#include <cstdint>
#include <cstddef>

#define NN 50000
#define NE 800000
#define NG 256
#define NLAY 7
#define NBLK 782   // 64-row tiles
#define CAP 18432  // bins capacity per dst-range

typedef float f32x4 __attribute__((ext_vector_type(4)));
typedef __bf16 bf16x8 __attribute__((ext_vector_type(8)));
typedef _Float16 h16x8 __attribute__((ext_vector_type(8)));

__device__ __forceinline__ float4 ld4(const float* p) { return *(const float4*)p; }
__device__ __forceinline__ void addh8(float4& x, float4& y, h16x8 v) {
  x.x += (float)v[0]; x.y += (float)v[1]; x.z += (float)v[2]; x.w += (float)v[3];
  y.x += (float)v[4]; y.y += (float)v[5]; y.z += (float)v[6]; y.w += (float)v[7];
}

// ---------------- init: zeros + hb=fp16(x) + W1/W2 -> MFMA-fragment order --------
// wf layout: pos = ((kc*16 + slot)*64 + lane)*8 + j, slot = (half*4+ct)*2 + hl.
// Lane's fragment is 16B at consecutive addresses across lanes -> coalesced loads,
// no LDS staging, no barriers in the MFMA phase.
__global__ void k_init(const float* __restrict__ x, const float* __restrict__ W1,
                       const float* __restrict__ W2, int* __restrict__ counts,
                       int* __restrict__ gcur, float* __restrict__ pooled,
                       _Float16* __restrict__ hb,
                       __bf16* __restrict__ w1f, __bf16* __restrict__ w2f) {
  int i = blockIdx.x * 256 + threadIdx.x;  // grid 25000 -> 6.4M
  if (i < NN) counts[i] = 0;
  if (i < 49) gcur[i] = i * CAP;
  if (i < NG * 1792) pooled[i] = 0.f;
  if (i < NN * 128) hb[i] = (_Float16)x[i];
  if (i < NLAY * 32768) {
    int l = i >> 15, pos = i & 32767;
    int j = pos & 7, ln = (pos >> 3) & 63, slot = (pos >> 9) & 15, kc = pos >> 13;
    int hl = slot & 1, ctp = (slot >> 1) & 3, hfp = slot >> 3;
    int n = hfp * 64 + ctp * 16 + (ln & 15);
    int k = kc * 32 + ((ln >> 4) << 3) + j;
    float a = W1[l * 16384 + k * 128 + n];
    float b = W2[l * 16384 + k * 128 + n];
    __bf16 ah = (__bf16)a, bh = (__bf16)b;
    w1f[i] = hl ? (__bf16)(a - (float)ah) : ah;
    w2f[i] = hl ? (__bf16)(b - (float)bh) : bh;
  }
}

__global__ void k_hist(const int* __restrict__ edge, int* __restrict__ counts) {
  int e = blockIdx.x * 256 + threadIdx.x;
  if (e < NE) atomicAdd(&counts[edge[NE + e]], 1);
}

// ---------------- parallel CSR scan ----------------
__global__ void k_part(const int* __restrict__ counts, int* __restrict__ bsum) {
  __shared__ int sm[256];
  int b = blockIdx.x, t = threadIdx.x;
  int i = b * 256 + t;
  sm[t] = (i < NN) ? counts[i] : 0;
  __syncthreads();
  for (int s = 128; s > 0; s >>= 1) {
    if (t < s) sm[t] += sm[t + s];
    __syncthreads();
  }
  if (t == 0) bsum[b] = sm[0];
}

__global__ void k_bscan(const int* __restrict__ bsum, int* __restrict__ boff,
                        int* __restrict__ row_ptr) {
  __shared__ int sm[256];
  int t = threadIdx.x;
  int v = (t < 196) ? bsum[t] : 0;
  sm[t] = v;
  __syncthreads();
  int val = v;
  for (int off = 1; off < 256; off <<= 1) {
    int o = (t >= off) ? sm[t - off] : 0;
    __syncthreads();
    val += o;
    sm[t] = val;
    __syncthreads();
  }
  if (t < 196) boff[t] = val - v;  // exclusive
  if (t == 255) row_ptr[NN] = val; // total = NE
}

__global__ void k_rowptr(const int* __restrict__ counts, const int* __restrict__ boff,
                         int* __restrict__ row_ptr) {
  __shared__ int sm[256];
  int b = blockIdx.x, t = threadIdx.x;
  int i = b * 256 + t;
  int c = (i < NN) ? counts[i] : 0;
  sm[t] = c;
  __syncthreads();
  int val = c;
  for (int off = 1; off < 256; off <<= 1) {
    int o = (t >= off) ? sm[t - off] : 0;
    __syncthreads();
    val += o;
    sm[t] = val;
    __syncthreads();
  }
  if (i < NN) row_ptr[i] = val - c + boff[b];
}

// ---------------- binned CSR build ----------------
__global__ __launch_bounds__(256) void k_binA(const int* __restrict__ edge,
                                              int* __restrict__ gcur,
                                              unsigned int* __restrict__ bins) {
  __shared__ int lh[49], lbase[49], lt[49];
  const int tid = threadIdx.x;
  const int e0 = blockIdx.x * 3125, e1 = e0 + 3125;
  if (tid < 49) { lh[tid] = 0; lt[tid] = 0; }
  __syncthreads();
  for (int e = e0 + tid; e < e1; e += 256)
    atomicAdd(&lh[edge[NE + e] >> 10], 1);
  __syncthreads();
  if (tid < 49) lbase[tid] = atomicAdd(&gcur[tid], lh[tid]);
  __syncthreads();
  for (int e = e0 + tid; e < e1; e += 256) {
    int dst = edge[NE + e], src = edge[e];
    int r = dst >> 10;
    int t = atomicAdd(&lt[r], 1);
    bins[lbase[r] + t] = ((unsigned)dst << 16) | (unsigned)src;
  }
}

__global__ __launch_bounds__(512) void k_binB(const int* __restrict__ row_ptr,
                                              const int* __restrict__ gcur,
                                              const unsigned int* __restrict__ bins,
                                              unsigned short* __restrict__ csr16) {
  __shared__ int lcur[1024];
  __shared__ unsigned short lcsr[24576];  // 48 KB
  const int blk = blockIdx.x, tid = threadIdx.x;
  const int base = blk << 10;
  const int nn = (base + 1024 <= NN) ? 1024 : (NN - base);
  const int seg0 = row_ptr[base];
  const int seg1 = row_ptr[(base + 1024 <= NN) ? (base + 1024) : NN];
  for (int i = tid; i < nn; i += 512) lcur[i] = row_ptr[base + i] - seg0;
  __syncthreads();
  const int tot = gcur[blk] - blk * CAP;
  for (int t = tid; t < tot; t += 512) {
    unsigned int p = bins[blk * CAP + t];
    int dst = (int)(p >> 16), src = (int)(p & 0xffffu);
    int pos = atomicAdd(&lcur[dst - base], 1);
    lcsr[pos] = (unsigned short)src;
  }
  __syncthreads();
  for (int i = tid; i < seg1 - seg0; i += 512) csr16[seg0 + i] = lcsr[i];
}

// ---------------- split fp32x8 -> bf16 hi/lo fragments ----------------
__device__ __forceinline__ void split8(const float4 v0, const float4 v1,
                                       bf16x8& hi, bf16x8& lo) {
  float f[8] = {v0.x, v0.y, v0.z, v0.w, v1.x, v1.y, v1.z, v1.w};
  #pragma unroll
  for (int j = 0; j < 8; ++j) {
    __bf16 h = (__bf16)f[j];
    hi[j] = h;
    lo[j] = (__bf16)(f[j] - (float)h);
  }
}

// ---------------- MFMA phase: barrier-free, frag-ordered global B loads ----------
__device__ __forceinline__ void mfma_phase(
    int tid, const __bf16* __restrict__ wf, float (*zs)[132], f32x4 acc[4])
{
  const int wv = tid >> 6, stripe = wv >> 1, half = wv & 1;
  const int lane = tid & 63, q = lane >> 4, m = lane & 15;
  #pragma unroll
  for (int kc = 0; kc < 4; ++kc) {
    const int k0 = kc * 32 + q * 8;
    float4 v0 = *(const float4*)&zs[stripe * 16 + m][k0];
    float4 v1 = *(const float4*)&zs[stripe * 16 + m][k0 + 4];
    bf16x8 ah, al;
    split8(v0, v1, ah, al);
    #pragma unroll
    for (int ct = 0; ct < 4; ++ct) {
      const int sbase = (half * 4 + ct) * 2;
      const __bf16* bp = wf + (((size_t)(kc * 16 + sbase) * 64 + lane) << 3);
      bf16x8 bh = *(const bf16x8*)bp;
      bf16x8 bl = *(const bf16x8*)(bp + 512);  // slot+1 = +64 lanes * 8
      acc[ct] = __builtin_amdgcn_mfma_f32_16x16x32_bf16(ah, bh, acc[ct], 0, 0, 0);
      acc[ct] = __builtin_amdgcn_mfma_f32_16x16x32_bf16(ah, bl, acc[ct], 0, 0, 0);
      acc[ct] = __builtin_amdgcn_mfma_f32_16x16x32_bf16(al, bh, acc[ct], 0, 0, 0);
    }
  }
  __syncthreads();  // zs dead after; callers reuse as scratch
}

// ---------------- FUSED1: fp16 gather (x4 unroll) -> LDS -> MFMA GEMM1 -> fp16 z1 --
__global__ __launch_bounds__(512) void k_fused1(
    const _Float16* __restrict__ hb, const int* __restrict__ row_ptr,
    const unsigned short* __restrict__ csr_src, const __bf16* __restrict__ wf,
    const float* __restrict__ bias, _Float16* __restrict__ zb,
    float* __restrict__ psum, float* __restrict__ psq)
{
  __shared__ float zs[64][132];
  const int tid = threadIdx.x;
  const int m0 = blockIdx.x * 64;

  // ---- phase 1: gather agg = h[r] + sum h[src]; 8 thr/row, 4 edges in flight ----
  {
    const int lr = tid >> 3;     // 0..63
    const int sub = tid & 7;     // 16 cols each
    const int r = m0 + lr;
    const int c0 = sub << 4;
    float4 a0 = make_float4(0,0,0,0), a1 = a0, a2 = a0, a3 = a0;
    float4 b0 = a0, b1 = a0, b2 = a0, b3 = a0;
    if (r < NN) {
      const _Float16* hp = hb + ((size_t)r << 7) + c0;
      addh8(a0, a1, *(const h16x8*)hp);
      addh8(a2, a3, *(const h16x8*)(hp + 8));
      int e = row_ptr[r], e1 = row_ptr[r + 1];
      for (; e + 3 < e1; e += 4) {
        const _Float16* p0 = hb + ((size_t)csr_src[e] << 7) + c0;
        const _Float16* p1 = hb + ((size_t)csr_src[e + 1] << 7) + c0;
        const _Float16* p2 = hb + ((size_t)csr_src[e + 2] << 7) + c0;
        const _Float16* p3 = hb + ((size_t)csr_src[e + 3] << 7) + c0;
        h16x8 v0a = *(const h16x8*)p0, v0b = *(const h16x8*)(p0 + 8);
        h16x8 v1a = *(const h16x8*)p1, v1b = *(const h16x8*)(p1 + 8);
        h16x8 v2a = *(const h16x8*)p2, v2b = *(const h16x8*)(p2 + 8);
        h16x8 v3a = *(const h16x8*)p3, v3b = *(const h16x8*)(p3 + 8);
        addh8(a0, a1, v0a); addh8(a2, a3, v0b);
        addh8(b0, b1, v1a); addh8(b2, b3, v1b);
        addh8(a0, a1, v2a); addh8(a2, a3, v2b);
        addh8(b0, b1, v3a); addh8(b2, b3, v3b);
      }
      for (; e < e1; ++e) {
        const _Float16* p0 = hb + ((size_t)csr_src[e] << 7) + c0;
        addh8(a0, a1, *(const h16x8*)p0);
        addh8(a2, a3, *(const h16x8*)(p0 + 8));
      }
      a0.x += b0.x; a0.y += b0.y; a0.z += b0.z; a0.w += b0.w;
      a1.x += b1.x; a1.y += b1.y; a1.z += b1.z; a1.w += b1.w;
      a2.x += b2.x; a2.y += b2.y; a2.z += b2.z; a2.w += b2.w;
      a3.x += b3.x; a3.y += b3.y; a3.z += b3.z; a3.w += b3.w;
    }
    *(float4*)&zs[lr][c0 + 0] = a0;
    *(float4*)&zs[lr][c0 + 4] = a1;
    *(float4*)&zs[lr][c0 + 8] = a2;
    *(float4*)&zs[lr][c0 + 12] = a3;
  }
  __syncthreads();

  // ---- phase 2: MFMA (barrier-free B) ----
  const int wv = tid >> 6, stripe = wv >> 1, half = wv & 1;
  const int lane = tid & 63, q = lane >> 4, m = lane & 15;
  f32x4 acc[4] = {};
  mfma_phase(tid, wf, zs, acc);

  // ---- epilogue: bias, fp16 z1 store, BN partials ----
  float* red_s = (float*)zs;          // 128*17
  float* red_q = red_s + 2176;        // 128*17
  const int sl = stripe * 4 + q;      // 16 partial slots per column
  #pragma unroll
  for (int ct = 0; ct < 4; ++ct) {
    const int col = half * 64 + ct * 16 + m;
    const float bb = bias[col];
    float s = 0.f, qq = 0.f;
    #pragma unroll
    for (int i = 0; i < 4; ++i) {
      int r = m0 + stripe * 16 + q * 4 + i;
      if (r < NN) {
        float o = acc[ct][i] + bb;
        zb[((size_t)r << 7) + col] = (_Float16)o;
        s += o; qq += o * o;
      }
    }
    red_s[col * 17 + sl] = s;
    red_q[col * 17 + sl] = qq;
  }
  __syncthreads();
  if (tid < 128) {
    float s = 0.f, qq = 0.f;
    #pragma unroll
    for (int k = 0; k < 16; ++k) {
      s += red_s[tid * 17 + k];
      qq += red_q[tid * 17 + k];
    }
    psum[blockIdx.x * 128 + tid] = s;
    psq[blockIdx.x * 128 + tid] = qq;
  }
}

// ---------------- BN finalize (parallel): one block per column ----------------
__global__ __launch_bounds__(256) void k_bnfin(
    const float* __restrict__ psum, const float* __restrict__ psq,
    const float* __restrict__ gamma, const float* __restrict__ beta,
    float* __restrict__ ab) {
  __shared__ float ss[256], sq[256];
  int col = blockIdx.x;   // 128
  int t = threadIdx.x;    // 256
  float s = 0.f, q = 0.f;
  for (int b = t; b < NBLK; b += 256) {
    s += psum[b * 128 + col];
    q += psq[b * 128 + col];
  }
  ss[t] = s; sq[t] = q;
  __syncthreads();
  for (int st = 128; st > 0; st >>= 1) {
    if (t < st) { ss[t] += ss[t + st]; sq[t] += sq[t + st]; }
    __syncthreads();
  }
  if (t == 0) {
    float mean = ss[0] * (1.f / NN);
    float var = sq[0] * (1.f / NN) - mean * mean;
    float rstd = rsqrtf(var + 1e-5f);
    float a = gamma[col] * rstd;
    ab[col] = a;
    ab[128 + col] = beta[col] - mean * a;
  }
}

// ---------------- FUSED2: affine+relu(fp16 z1) -> LDS -> MFMA GEMM2 -> fp16 h + pool
__global__ __launch_bounds__(512) void k_fused2(
    const _Float16* __restrict__ zb, const float* __restrict__ ab,
    const __bf16* __restrict__ wf, const float* __restrict__ bias,
    _Float16* __restrict__ hb, const int* __restrict__ batch,
    float* __restrict__ pooled, int layer)
{
  __shared__ float zs[64][132];
  const int tid = threadIdx.x;
  const int m0 = blockIdx.x * 64;

  // ---- phase 1: coalesced fp16 load + vector affine + relu -> zs ----
  {
    const int lr = tid >> 3;     // 0..63
    const int sub = tid & 7;     // 16 cols
    const int r = m0 + lr;
    const int c0 = sub << 4;
    h16x8 u0 = {}, u1 = {};
    if (r < NN) {
      const _Float16* rp = zb + ((size_t)r << 7) + c0;
      u0 = *(const h16x8*)rp;
      u1 = *(const h16x8*)(rp + 8);
    }
    float4 v0 = make_float4((float)u0[0], (float)u0[1], (float)u0[2], (float)u0[3]);
    float4 v1 = make_float4((float)u0[4], (float)u0[5], (float)u0[6], (float)u0[7]);
    float4 v2 = make_float4((float)u1[0], (float)u1[1], (float)u1[2], (float)u1[3]);
    float4 v3 = make_float4((float)u1[4], (float)u1[5], (float)u1[6], (float)u1[7]);
    float4 s0 = ld4(ab + c0), s1 = ld4(ab + c0 + 4);
    float4 s2 = ld4(ab + c0 + 8), s3 = ld4(ab + c0 + 12);
    float4 o0 = ld4(ab + 128 + c0), o1 = ld4(ab + 128 + c0 + 4);
    float4 o2 = ld4(ab + 128 + c0 + 8), o3 = ld4(ab + 128 + c0 + 12);
    float4 y0, y1, y2, y3;
    y0.x = fmaxf(fmaf(s0.x, v0.x, o0.x), 0.f); y0.y = fmaxf(fmaf(s0.y, v0.y, o0.y), 0.f);
    y0.z = fmaxf(fmaf(s0.z, v0.z, o0.z), 0.f); y0.w = fmaxf(fmaf(s0.w, v0.w, o0.w), 0.f);
    y1.x = fmaxf(fmaf(s1.x, v1.x, o1.x), 0.f); y1.y = fmaxf(fmaf(s1.y, v1.y, o1.y), 0.f);
    y1.z = fmaxf(fmaf(s1.z, v1.z, o1.z), 0.f); y1.w = fmaxf(fmaf(s1.w, v1.w, o1.w), 0.f);
    y2.x = fmaxf(fmaf(s2.x, v2.x, o2.x), 0.f); y2.y = fmaxf(fmaf(s2.y, v2.y, o2.y), 0.f);
    y2.z = fmaxf(fmaf(s2.z, v2.z, o2.z), 0.f); y2.w = fmaxf(fmaf(s2.w, v2.w, o2.w), 0.f);
    y3.x = fmaxf(fmaf(s3.x, v3.x, o3.x), 0.f); y3.y = fmaxf(fmaf(s3.y, v3.y, o3.y), 0.f);
    y3.z = fmaxf(fmaf(s3.z, v3.z, o3.z), 0.f); y3.w = fmaxf(fmaf(s3.w, v3.w, o3.w), 0.f);
    *(float4*)&zs[lr][c0 + 0] = y0;
    *(float4*)&zs[lr][c0 + 4] = y1;
    *(float4*)&zs[lr][c0 + 8] = y2;
    *(float4*)&zs[lr][c0 + 12] = y3;
  }
  __syncthreads();

  // ---- phase 2: MFMA (barrier-free B) ----
  const int wv = tid >> 6, stripe = wv >> 1, half = wv & 1;
  const int lane = tid & 63, q = lane >> 4, m = lane & 15;
  f32x4 acc[4] = {};
  mfma_phase(tid, wf, zs, acc);

  // ---- epilogue: bias+relu, fp16 h store, pooling ----
  int bg[4];
  #pragma unroll
  for (int i = 0; i < 4; ++i) {
    int r = m0 + stripe * 16 + q * 4 + i;
    bg[i] = (r < NN) ? batch[r] : -1;
  }
  #pragma unroll
  for (int ct = 0; ct < 4; ++ct) {
    const int col = half * 64 + ct * 16 + m;
    const float bb = bias[col];
    #pragma unroll
    for (int i = 0; i < 4; ++i) {
      int r = m0 + stripe * 16 + q * 4 + i;
      float v = fmaxf(acc[ct][i] + bb, 0.f);
      acc[ct][i] = v;
      if (r < NN) hb[((size_t)r << 7) + col] = (_Float16)v;
    }
  }

  int gstart = batch[m0];
  int gend = batch[(m0 + 63 < NN) ? (m0 + 63) : (NN - 1)];
  float* red_s = (float*)zs;          // 128*17
  float* red_m = red_s + 2176;        // 128*17
  const int sl = stripe * 4 + q;
  for (int g = gstart; g <= gend; ++g) {
    __syncthreads();
    #pragma unroll
    for (int ct = 0; ct < 4; ++ct) {
      const int col = half * 64 + ct * 16 + m;
      float s = 0.f, mx = 0.f;
      #pragma unroll
      for (int i = 0; i < 4; ++i) {
        if (bg[i] == g) { s += acc[ct][i]; mx = fmaxf(mx, acc[ct][i]); }
      }
      red_s[col * 17 + sl] = s;
      red_m[col * 17 + sl] = mx;
    }
    __syncthreads();
    if (tid < 128) {
      float s = 0.f, mx = 0.f;
      #pragma unroll
      for (int k = 0; k < 16; ++k) {
        s += red_s[tid * 17 + k];
        mx = fmaxf(mx, red_m[tid * 17 + k]);
      }
      if (s != 0.f) atomicAdd(&pooled[g * 1792 + layer * 128 + tid], s);
      if (mx != 0.f)
        atomicMax((int*)&pooled[g * 1792 + 896 + layer * 128 + tid], __float_as_int(mx));
    }
  }
}

// ---------------- Wl1 prep: transpose + split via LDS tiles ----------------
__global__ __launch_bounds__(256) void k_wl1prep(
    const float* __restrict__ Wl1, __bf16* __restrict__ wh, __bf16* __restrict__ wl) {
  __shared__ float tile[32][33];
  const int k0 = blockIdx.x * 32, n0 = blockIdx.y * 32;
  const int lr = threadIdx.x >> 5, lc = threadIdx.x & 31;
  #pragma unroll
  for (int it = 0; it < 4; ++it) {
    int rr = lr + it * 8;
    tile[rr][lc] = Wl1[(size_t)(k0 + rr) * 1792 + n0 + lc];
  }
  __syncthreads();
  #pragma unroll
  for (int it = 0; it < 4; ++it) {
    int rr = lr + it * 8;
    float v = tile[lc][rr];
    __bf16 h = (__bf16)v;
    wh[(size_t)(n0 + rr) * 1792 + k0 + lc] = h;
    wl[(size_t)(n0 + rr) * 1792 + k0 + lc] = (__bf16)(v - (float)h);
  }
}

// ---------------- MLP1 (MFMA split-bf16, split-K=4): part = pooled @ Wl1 ----------
__global__ __launch_bounds__(256) void k_mlp1a(
    const float* __restrict__ P, const __bf16* __restrict__ wh,
    const __bf16* __restrict__ wl, float* __restrict__ part)
{
  const int tid = threadIdx.x;
  const int n0 = blockIdx.x * 64;
  const int m0 = blockIdx.y * 64;
  const int kc = blockIdx.z;          // 0..3, chunk of 448 k
  const int kbase = kc * 448;
  const int w = tid >> 6, lane = tid & 63, q = lane >> 4, m = lane & 15;
  const int row = m0 + w * 16 + m;    // < 256 always
  f32x4 acc[4] = {};
  const float* rp = P + (size_t)row * 1792;
  #pragma unroll 2
  for (int ks = 0; ks < 14; ++ks) {
    const int k0 = kbase + ks * 32 + q * 8;
    float4 v0 = ld4(rp + k0), v1 = ld4(rp + k0 + 4);
    bf16x8 ah, al;
    split8(v0, v1, ah, al);
    #pragma unroll
    for (int ct = 0; ct < 4; ++ct) {
      const int n = n0 + ct * 16 + m;
      bf16x8 bh = *(const bf16x8*)(wh + (size_t)n * 1792 + k0);
      bf16x8 bl = *(const bf16x8*)(wl + (size_t)n * 1792 + k0);
      acc[ct] = __builtin_amdgcn_mfma_f32_16x16x32_bf16(ah, bh, acc[ct], 0, 0, 0);
      acc[ct] = __builtin_amdgcn_mfma_f32_16x16x32_bf16(ah, bl, acc[ct], 0, 0, 0);
      acc[ct] = __builtin_amdgcn_mfma_f32_16x16x32_bf16(al, bh, acc[ct], 0, 0, 0);
    }
  }
  float* pp = part + (size_t)kc * 458752;
  #pragma unroll
  for (int ct = 0; ct < 4; ++ct) {
    const int n = n0 + ct * 16 + m;
    #pragma unroll
    for (int i = 0; i < 4; ++i) {
      int r = m0 + w * 16 + q * 4 + i;
      pp[(size_t)r * 1792 + n] = acc[ct][i];
    }
  }
}

__global__ void k_mlp1b(const float* __restrict__ part, const float* __restrict__ bl1,
                        float* __restrict__ hfin) {
  int idx = blockIdx.x * 256 + threadIdx.x;
  int n = idx % 1792;
  float s = bl1[n];
  #pragma unroll
  for (int kc = 0; kc < 4; ++kc) s += part[(size_t)kc * 458752 + idx];
  hfin[idx] = fmaxf(s, 0.f);
}

__global__ void k_mlp2(const float* __restrict__ hfin, const float* __restrict__ Wl2,
                       const float* __restrict__ bl2, float* __restrict__ out) {
  __shared__ float red[256];
  int g = blockIdx.x, t = threadIdx.x;
  float p = 0.f;
  for (int k = t; k < 1792; k += 256) p += hfin[(size_t)g * 1792 + k] * Wl2[k];
  red[t] = p;
  __syncthreads();
  for (int s = 128; s > 0; s >>= 1) {
    if (t < s) red[t] += red[t + s];
    __syncthreads();
  }
  if (t == 0) {
    float l = red[0] + bl2[0];
    out[g] = 1.f / (1.f + expf(-l));
    out[NG + g] = l;
  }
}

// ---------------- launch ----------------
extern "C" void kernel_launch(void* const* d_in, const int* in_sizes, int n_in,
                              void* d_out, int out_size, void* d_ws, size_t ws_size,
                              hipStream_t stream) {
  const float* x     = (const float*)d_in[0];
  const int*   edge  = (const int*)d_in[1];
  const int*   batch = (const int*)d_in[2];
  const float* W1    = (const float*)d_in[3];
  const float* b1    = (const float*)d_in[4];
  const float* gamma = (const float*)d_in[5];
  const float* beta  = (const float*)d_in[6];
  const float* W2    = (const float*)d_in[7];
  const float* b2    = (const float*)d_in[8];
  const float* Wl1   = (const float*)d_in[9];
  const float* bl1   = (const float*)d_in[10];
  const float* Wl2   = (const float*)d_in[11];
  const float* bl2   = (const float*)d_in[12];
  float* out = (float*)d_out;

  int* wsi = (int*)d_ws;
  int* row_ptr = wsi;                 // 50048
  int* counts  = wsi + 50048;         // 50048
  int* bsum    = wsi + 100096;        // 256
  int* boff    = wsi + 100352;        // 256
  int* gcur    = wsi + 100608;        // 64 (pad to 100864)
  unsigned short* csr16 = (unsigned short*)(wsi + 100864);  // 800000 u16
  float* wsf   = (float*)(wsi + 950912);
  // float-region layout:
  _Float16* zb     = (_Float16*)wsf;            // [50000,128] fp16 z1 (3.2M floats)
  _Float16* hb     = (_Float16*)(wsf + 6400000);// [50000,128] fp16 h (3.2M floats)
  float*    part   = wsf + 9600000;             // [4][256][1792]
  float*    psum   = wsf + 12800000;            // [782,128]
  float*    psq    = wsf + 12900096;            // [782,128]
  float*    ab     = wsf + 13000192;            // [2,128]
  float*    pooled = wsf + 13000448;            // [256,1792] -> ends 13459200
  __bf16*   w1f    = (__bf16*)(wsf + 13459200); // 7*32768 bf16 frag-ordered
  __bf16*   w2f    = (__bf16*)(wsf + 13573888); // 7*32768 bf16 -> ends 13688576
  // bins aliases zb region (dead until first fused1; binB completes before layers)
  unsigned int* bins = (unsigned int*)wsf;      // 49*18432 u32 = 3.6 MB << zb size
  // post-layer aliases (zb region dead after last k_fused2):
  __bf16*   wl1h   = (__bf16*)wsf;              // 1792*1792 bf16
  __bf16*   wl1l   = (__bf16*)(wsf + 1605632);  // ends 3,211,264
  float*    hfin   = wsf + 4000000;             // [256,1792]

  // prep: zeros + x->fp16 + frag-ordered W split; degree hist; CSR scan; binned fill
  k_init<<<25000, 256, 0, stream>>>(x, W1, W2, counts, gcur, pooled, hb, w1f, w2f);
  k_hist<<<3125, 256, 0, stream>>>(edge, counts);
  k_part<<<196, 256, 0, stream>>>(counts, bsum);
  k_bscan<<<1, 256, 0, stream>>>(bsum, boff, row_ptr);
  k_rowptr<<<196, 256, 0, stream>>>(counts, boff, row_ptr);
  k_binA<<<256, 256, 0, stream>>>(edge, gcur, bins);
  k_binB<<<49, 512, 0, stream>>>(row_ptr, gcur, bins, csr16);

  for (int i = 0; i < NLAY; ++i) {
    k_fused1<<<NBLK, 512, 0, stream>>>(hb, row_ptr, csr16, w1f + i * 32768,
                                       b1 + i * 128, zb, psum, psq);
    k_bnfin<<<128, 256, 0, stream>>>(psum, psq, gamma + i * 128, beta + i * 128, ab);
    k_fused2<<<NBLK, 512, 0, stream>>>(zb, ab, w2f + i * 32768,
                                       b2 + i * 128, hb, batch, pooled, i);
  }
  // MLP head (zb region reused for Wl1 split + hfin)
  k_wl1prep<<<dim3(56, 56), 256, 0, stream>>>(Wl1, wl1h, wl1l);
  k_mlp1a<<<dim3(28, 4, 4), 256, 0, stream>>>(pooled, wl1h, wl1l, part);
  k_mlp1b<<<1792, 256, 0, stream>>>(part, bl1, hfin);
  k_mlp2<<<256, 256, 0, stream>>>(hfin, Wl2, bl2, out);
}